// Round 4
// baseline (889.629 us; speedup 1.0000x reference)
//
#include <hip/hip_runtime.h>
#include <hip/hip_bf16.h>

#define B_ 4
#define H_ 32
#define S_ 2048
#define D_ 128
#define DM_ 4096
#define BH_ (B_*H_)
#define M_ (B_*S_)   // 8192 rows of final GEMM

typedef short bf16x8 __attribute__((ext_vector_type(8)));
typedef short s16x4  __attribute__((ext_vector_type(4)));
typedef float f32x4  __attribute__((ext_vector_type(4)));

__device__ __forceinline__ float phi_f(float x) {
    // elu(x)+1
    return x > 0.f ? x + 1.f : __expf(x);
}

__device__ __forceinline__ short f2b(float x) {
    __hip_bfloat16 h = __float2bfloat16(x);
    return *(short*)&h;
}

__device__ __forceinline__ void gl_lds16(void* lds_uniform, const void* gptr) {
    __builtin_amdgcn_global_load_lds(
        (const __attribute__((address_space(1))) void*)gptr,
        (__attribute__((address_space(3))) void*)lds_uniform,
        16, 0, 0);
}

// ---------------------------------------------------------------------------
// K1 (MFMA): parts[split][bh][v][k] = sum_{s in split} V[bh][s][v]*phi(K[bh][s][k])
//            nrm[bh][k]            += sum_s phi(K[bh][s][k])   (atomic, 64KB)
// grid (4 s-splits, 128 bh), 256 threads (4 waves, each a 64v x 64k quadrant).
// Plain stores to per-split partials (no 8M atomics, no 8.4MB memset).
// ---------------------------------------------------------------------------
__global__ __launch_bounds__(256) void k1_memory(
    const float* __restrict__ Kin, const float* __restrict__ Vin,
    float* __restrict__ parts, float* __restrict__ nrm)
{
    const int split = blockIdx.x;   // 0..3, 512 s-rows each
    const int bh = blockIdx.y;
    const int t = threadIdx.x;
    const int wave = t >> 6, lane = t & 63;
    const int lm = lane & 15, quad = lane >> 4;
    const int wm = wave >> 1, wn = wave & 1;    // v-half, k-half

    __shared__ __hip_bfloat16 sVt[128*72];      // [v][s]  18KB
    __shared__ __hip_bfloat16 sKt[128*72];      // [k][s]  18KB

    const long base = (long)bh * S_ * D_ + (long)split * (S_/4) * D_;
    const float* Kp = Kin + base;
    const float* Vp = Vin + base;

    f32x4 acc[4][4];
#pragma unroll
    for (int i = 0; i < 4; ++i)
#pragma unroll
        for (int j = 0; j < 4; ++j) { f32x4 z = {0.f,0.f,0.f,0.f}; acc[i][j] = z; }

    float na[2][4] = {{0.f,0.f,0.f,0.f},{0.f,0.f,0.f,0.f}};

    const int si  = t & 15;          // s-quad within chunk (0..15)
    const int dj0 = t >> 4;          // 0..15 (d-quad base)

    for (int c = 0; c < 8; ++c) {    // 8 chunks of 64 s-rows
        const int s0 = c*64 + si*4;
        __syncthreads();             // previous chunk's readers done
#pragma unroll
        for (int m = 0; m < 2; ++m) {
            const int dj = dj0 + 16*m;              // d-quad 0..31
            const float* gK = Kp + (long)s0*D_ + dj*4;
            const float* gV = Vp + (long)s0*D_ + dj*4;
            float4 krv[4], vrv[4];
#pragma unroll
            for (int r = 0; r < 4; ++r) {
                krv[r] = *(const float4*)(gK + (long)r*D_);
                vrv[r] = *(const float4*)(gV + (long)r*D_);
            }
            const float* kf = (const float*)krv;    // kf[r*4+cc]
            const float* vf = (const float*)vrv;
#pragma unroll
            for (int cc = 0; cc < 4; ++cc) {
                float p0 = phi_f(kf[0*4+cc]), p1 = phi_f(kf[1*4+cc]);
                float p2 = phi_f(kf[2*4+cc]), p3 = phi_f(kf[3*4+cc]);
                na[m][cc] += p0 + p1 + p2 + p3;
                s16x4 pw; pw[0]=f2b(p0); pw[1]=f2b(p1); pw[2]=f2b(p2); pw[3]=f2b(p3);
                s16x4 vw; vw[0]=f2b(vf[0*4+cc]); vw[1]=f2b(vf[1*4+cc]);
                          vw[2]=f2b(vf[2*4+cc]); vw[3]=f2b(vf[3*4+cc]);
                const int d = dj*4 + cc;
                *(s16x4*)(sKt + d*72 + si*4) = pw;
                *(s16x4*)(sVt + d*72 + si*4) = vw;
            }
        }
        __syncthreads();
#pragma unroll
        for (int kh = 0; kh < 2; ++kh) {
            const int scol = kh*32 + quad*8;
            bf16x8 af[4], bfr[4];
#pragma unroll
            for (int x = 0; x < 4; ++x) {
                af[x]  = *(const bf16x8*)(sVt + (wm*64 + x*16 + lm)*72 + scol);
                bfr[x] = *(const bf16x8*)(sKt + (wn*64 + x*16 + lm)*72 + scol);
            }
#pragma unroll
            for (int mt = 0; mt < 4; ++mt)
#pragma unroll
                for (int nt = 0; nt < 4; ++nt)
                    acc[mt][nt] = __builtin_amdgcn_mfma_f32_16x16x32_bf16(
                        af[mt], bfr[nt], acc[mt][nt], 0, 0, 0);
        }
    }

    // norm: reduce na over the 16 threads sharing dj (lane bits 0-3 = si)
#pragma unroll
    for (int m = 0; m < 2; ++m)
#pragma unroll
        for (int cc = 0; cc < 4; ++cc) {
            float v = na[m][cc];
            v += __shfl_xor(v, 1); v += __shfl_xor(v, 2);
            v += __shfl_xor(v, 4); v += __shfl_xor(v, 8);
            if (si == 0)
                atomicAdd(&nrm[bh*D_ + (dj0 + 16*m)*4 + cc], v);
        }

    // epilogue: plain stores to this split's partial. C/D: col=k, row=v (quad*4+reg)
    float* mp = parts + ((long)split*BH_ + bh) * (D_*D_);
#pragma unroll
    for (int mt = 0; mt < 4; ++mt)
#pragma unroll
        for (int nt = 0; nt < 4; ++nt) {
            const int kcol = wn*64 + nt*16 + lm;
#pragma unroll
            for (int r = 0; r < 4; ++r) {
                const int vrow = wm*64 + mt*16 + quad*4 + r;
                mp[vrow*D_ + kcol] = acc[mt][nt][r];
            }
        }
}

// ---------------------------------------------------------------------------
// K1b: memTb[bh][row][seg] (bf16, 16B segs, PRE-SWIZZLED seg^(row&15)) =
//      sum over 4 split partials. Lets k2 stage via linear global_load_lds
// while its ds_reads apply the same seg-XOR (rule #21: src and read swizzle
// are the same involution, LDS dest linear).
// 262144 segs -> 1024 blocks x 256.
// ---------------------------------------------------------------------------
__global__ __launch_bounds__(256) void k1b_finalize(
    const float* __restrict__ parts, __hip_bfloat16* __restrict__ memTb)
{
    const long g = (long)blockIdx.x*256 + threadIdx.x;  // 0..262143
    const int bh  = (int)(g >> 11);
    const int rem = (int)(g & 2047);
    const int row = rem >> 4, seg = rem & 15;
    const int srcSeg = seg ^ (row & 15);
    const long sbase = (long)bh*(D_*D_) + row*D_ + srcSeg*8;

    f32x4 s0 = {0.f,0.f,0.f,0.f}, s1 = {0.f,0.f,0.f,0.f};
#pragma unroll
    for (int sp = 0; sp < 4; ++sp) {
        const float* p = parts + (long)sp*BH_*(D_*D_) + sbase;
        s0 += *(const f32x4*)p;
        s1 += *(const f32x4*)(p + 4);
    }
    bf16x8 ob;
#pragma unroll
    for (int j = 0; j < 4; ++j) { ob[j] = f2b(s0[j]); ob[4+j] = f2b(s1[j]); }
    *(bf16x8*)(memTb + g*8) = ob;
}

// ---------------------------------------------------------------------------
// K2 (MFMA): retrieved = phi(Q) @ mem ; denom = phi(Q)·norm ;
//            attn = gw*retrieved/denom + lw*local ; bf16 out to [B,S,H*D]
// grid (16 s-blocks of 128 rows, 128 bh), 256 threads (4 waves, 64s x 64v).
// sM staged via 8 global_load_lds from pre-swizzled memTb (zero VALU, issued
// first so latency hides under Q's phi). Q staged manually (phi) with the
// same seg-XOR swizzle. Epilogue: acc*scale -> LDS fp32 [128][132] -> fused
// vectorized pass (float4 L loads, 16B bf16 stores): 24 VMEM instr/thread
// instead of 128 scalar ones.
// ---------------------------------------------------------------------------
__global__ __launch_bounds__(256) void k2_retrieve(
    const float* __restrict__ Qin, const float* __restrict__ Lin,
    const float* __restrict__ bal,
    const __hip_bfloat16* __restrict__ memTb, const float* __restrict__ nrm,
    __hip_bfloat16* __restrict__ attnB)
{
    const int sc = blockIdx.x;    // 0..15
    const int bh = blockIdx.y;
    const int b = bh >> 5, h = bh & 31;
    const int t = threadIdx.x;
    const int wave = t >> 6, lane = t & 63;
    const int lm = lane & 15, quad = lane >> 4;
    const int wm = wave >> 1, wn = wave & 1;    // s-half, v-half

    __shared__ char smem[128*132*4];            // 67,584 B (staging + epilogue)
    __hip_bfloat16* sQ = (__hip_bfloat16*)smem;             // 32 KB [s][k] swz
    __hip_bfloat16* sM = (__hip_bfloat16*)(smem + 32768);   // 32 KB [v][k] swz
    float* sOut = (float*)smem;                              // epilogue reuse
    __shared__ float sDen[128];

    const float* Qp = Qin + (long)bh*S_*D_ + (long)sc*128*D_;
    const float* Lp = Lin + (long)bh*S_*D_ + (long)sc*128*D_;
    const __hip_bfloat16* mb = memTb + (long)bh*(D_*D_);

    // 1) issue sM staging first (HBM/L2 latency hides under Q's phi work)
#pragma unroll
    for (int i = 0; i < 8; ++i)
        gl_lds16((void*)(sM + (i*256 + wave*64)*8),
                 (const void*)(mb + (long)(i*256 + wave*64 + lane)*8));

    // 2) Q: phi + denom partial + bf16 swizzled write
    const int kq = t & 31;                       // k-quad (constant across i)
    const float4 nq = *(const float4*)(nrm + bh*D_ + kq*4);
#pragma unroll
    for (int i = 0; i < 16; ++i) {
        const int idx = t + i*256;               // float4 index over 128x32
        const int row = idx >> 5;                // = (t>>5) + 8i
        float4 qv = *(const float4*)(Qp + (long)idx*4);
        float p0 = phi_f(qv.x), p1 = phi_f(qv.y), p2 = phi_f(qv.z), p3 = phi_f(qv.w);
        float part = p0*nq.x + p1*nq.y + p2*nq.z + p3*nq.w;
        part += __shfl_xor(part, 1);  part += __shfl_xor(part, 2);
        part += __shfl_xor(part, 4);  part += __shfl_xor(part, 8);
        part += __shfl_xor(part, 16);
        if (kq == 0) sDen[row] = part;
        const int seg = kq >> 1, half = kq & 1;
        const int off = row*128 + ((seg ^ (row & 15)) << 3) + half*4;
        s16x4 qw; qw[0]=f2b(p0); qw[1]=f2b(p1); qw[2]=f2b(p2); qw[3]=f2b(p3);
        *(s16x4*)(sQ + off) = qw;
    }
    __syncthreads();   // drains vmcnt(0): sM staged; sQ/sDen visible

    f32x4 acc[4][4];
#pragma unroll
    for (int i = 0; i < 4; ++i)
#pragma unroll
        for (int j = 0; j < 4; ++j) { f32x4 z = {0.f,0.f,0.f,0.f}; acc[i][j] = z; }

#pragma unroll
    for (int kh = 0; kh < 4; ++kh) {
        const int segk = kh*4 + quad;            // 16B k-seg 0..15
        bf16x8 af[4], bfr[4];
#pragma unroll
        for (int x = 0; x < 4; ++x) {
            const int srow = wm*64 + x*16 + lm;
            af[x]  = *(const bf16x8*)(sQ + srow*128 + ((segk ^ (srow & 15)) << 3));
            const int vrow = wn*64 + x*16 + lm;
            bfr[x] = *(const bf16x8*)(sM + vrow*128 + ((segk ^ (vrow & 15)) << 3));
        }
#pragma unroll
        for (int mt = 0; mt < 4; ++mt)
#pragma unroll
            for (int nt = 0; nt < 4; ++nt)
                acc[mt][nt] = __builtin_amdgcn_mfma_f32_16x16x32_bf16(
                    af[mt], bfr[nt], acc[mt][nt], 0, 0, 0);
    }

    const float bv = bal[h];
    const float gw = 1.f/(1.f+__expf(-bv));
    const float lw = 1.f/(1.f+__expf(-(1.f-bv)));

    // ---- epilogue pass A: scaled acc -> LDS fp32 [128][132] (2-way = free)
    __syncthreads();   // all waves done reading sQ/sM before overwrite
#pragma unroll
    for (int mt = 0; mt < 4; ++mt)
#pragma unroll
        for (int r = 0; r < 4; ++r) {
            const int srow = wm*64 + mt*16 + quad*4 + r;
            const float scale = gw / sDen[srow];
#pragma unroll
            for (int nt = 0; nt < 4; ++nt)
                sOut[srow*132 + wn*64 + nt*16 + lm] = acc[mt][nt][r]*scale;
        }
    __syncthreads();

    // ---- epilogue pass B: fused + vectorized. Per iter: 16 lanes cover one
    // row's 256B output contiguously; 4 rows per instruction.
    const int seg = t & 15;                      // 16B out-seg (8 bf16)
#pragma unroll
    for (int i = 0; i < 8; ++i) {
        const int row = (t >> 4) + i*16;         // 0..127
        const float* Lr = Lp + (long)row*D_ + seg*8;
        const float* Or = sOut + row*132 + seg*8;
        float4 l0 = *(const float4*)Lr;
        float4 l1 = *(const float4*)(Lr + 4);
        f32x4 o0 = *(const f32x4*)Or;
        f32x4 o1 = *(const f32x4*)(Or + 4);
        bf16x8 ob;
        ob[0] = f2b(o0[0] + lw*l0.x); ob[1] = f2b(o0[1] + lw*l0.y);
        ob[2] = f2b(o0[2] + lw*l0.z); ob[3] = f2b(o0[3] + lw*l0.w);
        ob[4] = f2b(o1[0] + lw*l1.x); ob[5] = f2b(o1[1] + lw*l1.y);
        ob[6] = f2b(o1[2] + lw*l1.z); ob[7] = f2b(o1[3] + lw*l1.w);
        const long oidx = ((long)b*S_ + sc*128 + row)*DM_ + h*D_ + seg*8;
        *(bf16x8*)(attnB + oidx) = ob;
    }
}

// ---------------------------------------------------------------------------
// w_o fp32 -> bf16
// ---------------------------------------------------------------------------
__global__ __launch_bounds__(256) void kconv(
    const float* __restrict__ w, __hip_bfloat16* __restrict__ wb)
{
    long i = ((long)blockIdx.x*256 + threadIdx.x)*4;
    float4 f = *(const float4*)(w + i);
    __hip_bfloat16 ob[4] = {__float2bfloat16(f.x), __float2bfloat16(f.y),
                            __float2bfloat16(f.z), __float2bfloat16(f.w)};
    *(uint2*)(wb + i) = *(uint2*)ob;
}

// ---------------------------------------------------------------------------
// K3: Y[8192,4096] = X[8192,4096] @ W[4096,4096]^T   (bf16 MFMA, fp32 out)
// 256x256 8-phase template: BK=64, 8 waves (2Mx4N), 512 threads, 128KiB LDS
// dbuf, counted vmcnt(8) at tile boundaries, raw s_barrier, setprio, seg-XOR
// swizzle (seg' = seg ^ (row&7)) via pre-swizzled global source. (UNCHANGED
// this round — control for the k1/k2 rewrite.)
// ---------------------------------------------------------------------------
#define GBM 256
#define GBN 256
#define GBK 64
#define GNT (DM_/GBK)   // 64 K-tiles

__device__ __forceinline__ bf16x8 ldfrag(const __hip_bfloat16* base, int row, int k) {
    const int kk = k ^ ((row & 7) << 3);
    return *(const bf16x8*)(base + row * GBK + kk);
}

__device__ __forceinline__ void stage_tile(
    const __hip_bfloat16* __restrict__ X, const __hip_bfloat16* __restrict__ W,
    __hip_bfloat16* sAb, __hip_bfloat16* sBb,
    int m0, int n0, int kb, int wave, int lane)
{
#pragma unroll
    for (int r = 0; r < 4; ++r) {
        const int c   = r * 512 + wave * 64 + lane;        // 16B chunk id 0..2047
        const int row = c >> 3;
        const int ko  = ((c & 7) ^ (row & 7)) * 8;         // pre-swizzled source seg
        gl_lds16((void*)(sAb + (r * 512 + wave * 64) * 8),
                 (const void*)(X + (long)(m0 + row) * DM_ + kb + ko));
    }
#pragma unroll
    for (int r = 0; r < 4; ++r) {
        const int c   = r * 512 + wave * 64 + lane;
        const int row = c >> 3;
        const int ko  = ((c & 7) ^ (row & 7)) * 8;
        gl_lds16((void*)(sBb + (r * 512 + wave * 64) * 8),
                 (const void*)(W + (long)(n0 + row) * DM_ + kb + ko));
    }
}

__global__ __launch_bounds__(512, 2) void k3_gemm(
    const __hip_bfloat16* __restrict__ X,
    const __hip_bfloat16* __restrict__ W,
    float* __restrict__ Y)
{
    __shared__ alignas(16) __hip_bfloat16 sA[2][GBM * GBK];   // 64 KiB
    __shared__ alignas(16) __hip_bfloat16 sB[2][GBN * GBK];   // 64 KiB

    const int tid = threadIdx.x;
    const int wave = tid >> 6, lane = tid & 63;
    const int lm = lane & 15, quad = lane >> 4;
    const int wm = wave >> 2, wn = wave & 3;     // 2M x 4N waves

    const int orig = blockIdx.x;
    const int wg = (orig & 7) * 64 + (orig >> 3);
    const int m0 = (wg >> 4) * GBM;
    const int n0 = (wg & 15) * GBN;

    f32x4 acc[8][4];
#pragma unroll
    for (int i = 0; i < 8; ++i)
#pragma unroll
        for (int j = 0; j < 4; ++j) { f32x4 z = {0.f,0.f,0.f,0.f}; acc[i][j] = z; }

    const int ar0 = wm * 128 + lm;
    const int br0 = wn * 64 + lm;
    const int kq  = quad * 8;

    stage_tile(X, W, sA[0], sB[0], m0, n0, 0, wave, lane);
    stage_tile(X, W, sA[1], sB[1], m0, n0, GBK, wave, lane);
    asm volatile("s_waitcnt vmcnt(8)" ::: "memory");
    __builtin_amdgcn_s_barrier();

    bf16x8 a[4][2], b[4][2];

    for (int t = 0; t < GNT; ++t) {
        const int cur = t & 1;
        const __hip_bfloat16* As = sA[cur];
        const __hip_bfloat16* Bs = sB[cur];

        // phase 0
#pragma unroll
        for (int mf = 0; mf < 4; ++mf)
#pragma unroll
            for (int kh = 0; kh < 2; ++kh)
                a[mf][kh] = ldfrag(As, ar0 + mf * 16, kh * 32 + kq);
#pragma unroll
        for (int nf = 0; nf < 2; ++nf)
#pragma unroll
            for (int kh = 0; kh < 2; ++kh)
                b[nf][kh] = ldfrag(Bs, br0 + nf * 16, kh * 32 + kq);
        __builtin_amdgcn_s_barrier();
        asm volatile("s_waitcnt lgkmcnt(0)" ::: "memory");
        __builtin_amdgcn_sched_barrier(0);
        __builtin_amdgcn_s_setprio(1);
#pragma unroll
        for (int mf = 0; mf < 4; ++mf)
#pragma unroll
            for (int nf = 0; nf < 2; ++nf)
#pragma unroll
                for (int kh = 0; kh < 2; ++kh)
                    acc[mf][nf] = __builtin_amdgcn_mfma_f32_16x16x32_bf16(
                        a[mf][kh], b[nf][kh], acc[mf][nf], 0, 0, 0);
        __builtin_amdgcn_s_setprio(0);
        __builtin_amdgcn_s_barrier();

        // phase 1
#pragma unroll
        for (int nf = 2; nf < 4; ++nf)
#pragma unroll
            for (int kh = 0; kh < 2; ++kh)
                b[nf][kh] = ldfrag(Bs, br0 + nf * 16, kh * 32 + kq);
        __builtin_amdgcn_s_barrier();
        asm volatile("s_waitcnt lgkmcnt(0)" ::: "memory");
        __builtin_amdgcn_sched_barrier(0);
        __builtin_amdgcn_s_setprio(1);
#pragma unroll
        for (int mf = 0; mf < 4; ++mf)
#pragma unroll
            for (int nf = 2; nf < 4; ++nf)
#pragma unroll
                for (int kh = 0; kh < 2; ++kh)
                    acc[mf][nf] = __builtin_amdgcn_mfma_f32_16x16x32_bf16(
                        a[mf][kh], b[nf][kh], acc[mf][nf], 0, 0, 0);
        __builtin_amdgcn_s_setprio(0);
        __builtin_amdgcn_s_barrier();

        // phase 2
#pragma unroll
        for (int mf = 0; mf < 4; ++mf)
#pragma unroll
            for (int kh = 0; kh < 2; ++kh)
                a[mf][kh] = ldfrag(As, ar0 + 64 + mf * 16, kh * 32 + kq);
        __builtin_amdgcn_s_barrier();
        asm volatile("s_waitcnt lgkmcnt(0)" ::: "memory");
        __builtin_amdgcn_sched_barrier(0);
        __builtin_amdgcn_s_setprio(1);
#pragma unroll
        for (int mf = 0; mf < 4; ++mf)
#pragma unroll
            for (int nf = 0; nf < 2; ++nf)
#pragma unroll
                for (int kh = 0; kh < 2; ++kh)
                    acc[4 + mf][nf] = __builtin_amdgcn_mfma_f32_16x16x32_bf16(
                        a[mf][kh], b[nf][kh], acc[4 + mf][nf], 0, 0, 0);
        __builtin_amdgcn_s_setprio(0);
        __builtin_amdgcn_s_barrier();

        // phase 3: stage t+2 into cur, counted vmcnt boundary
        if (t + 2 < GNT)
            stage_tile(X, W, sA[cur], sB[cur], m0, n0, (t + 2) * GBK, wave, lane);
        __builtin_amdgcn_s_barrier();
        __builtin_amdgcn_s_setprio(1);
#pragma unroll
        for (int mf = 0; mf < 4; ++mf)
#pragma unroll
            for (int nf = 2; nf < 4; ++nf)
#pragma unroll
                for (int kh = 0; kh < 2; ++kh)
                    acc[4 + mf][nf] = __builtin_amdgcn_mfma_f32_16x16x32_bf16(
                        a[mf][kh], b[nf][kh], acc[4 + mf][nf], 0, 0, 0);
        __builtin_amdgcn_s_setprio(0);
        if (t + 2 < GNT)
            asm volatile("s_waitcnt vmcnt(8)" ::: "memory");
        else
            asm volatile("s_waitcnt vmcnt(0)" ::: "memory");
        __builtin_amdgcn_s_barrier();
    }

#pragma unroll
    for (int mf = 0; mf < 8; ++mf) {
        const int row = m0 + wm * 128 + mf * 16 + quad * 4;
#pragma unroll
        for (int nf = 0; nf < 4; ++nf) {
            const int col = n0 + wn * 64 + nf * 16 + lm;
#pragma unroll
            for (int r = 0; r < 4; ++r)
                Y[(long)(row + r) * DM_ + col] = acc[mf][nf][r];
        }
    }
}

// ---------------------------------------------------------------------------
extern "C" void kernel_launch(void* const* d_in, const int* in_sizes, int n_in,
                              void* d_out, int out_size, void* d_ws, size_t ws_size,
                              hipStream_t stream) {
    const float* Q   = (const float*)d_in[0];
    const float* K   = (const float*)d_in[1];
    const float* V   = (const float*)d_in[2];
    const float* L   = (const float*)d_in[3];
    const float* bal = (const float*)d_in[4];
    const float* Wo  = (const float*)d_in[5];
    float* Y = (float*)d_out;

    char* ws = (char*)d_ws;
    // [0, 32MB): parts (k1 out, k1b in) ... THEN woB (kconv out, k3 in) —
    // lifetimes disjoint on the stream (k1 -> k1b -> kconv -> k2 -> k3).
    float* parts = (float*)ws;                                   // 33,554,432 B
    __hip_bfloat16* woB = (__hip_bfloat16*)ws;                   // same region
    float* nrm   = (float*)(ws + 33554432);                      //    65,536 B
    __hip_bfloat16* memTb = (__hip_bfloat16*)(ws + 33619968);    //  4,194,304 B
    __hip_bfloat16* attnB = (__hip_bfloat16*)(ws + 37814272);    // 67,108,864 B
    // total 104,923,136 B

    // only the 64KB norm accumulator needs zeroing now
    hipMemsetAsync(nrm, 0, 65536, stream);

    k1_memory<<<dim3(4, BH_), 256, 0, stream>>>(K, V, parts, nrm);
    k1b_finalize<<<1024, 256, 0, stream>>>(parts, memTb);
    kconv<<<DM_*DM_/4/256, 256, 0, stream>>>(Wo, woB);
    k2_retrieve<<<dim3(S_/128, BH_), 256, 0, stream>>>(Q, L, bal, memTb, nrm, attnB);
    k3_gemm<<<dim3(512), 512, 0, stream>>>(attnB, woB, Y);
}

// Round 5
// 829.131 us; speedup vs baseline: 1.0730x; 1.0730x over previous
//
#include <hip/hip_runtime.h>
#include <hip/hip_bf16.h>

#define B_ 4
#define H_ 32
#define S_ 2048
#define D_ 128
#define DM_ 4096
#define BH_ (B_*H_)
#define M_ (B_*S_)   // 8192 rows of final GEMM

typedef short bf16x8 __attribute__((ext_vector_type(8)));
typedef short s16x4  __attribute__((ext_vector_type(4)));
typedef float f32x4  __attribute__((ext_vector_type(4)));

__device__ __forceinline__ float phi_f(float x) {
    // elu(x)+1
    return x > 0.f ? x + 1.f : __expf(x);
}

__device__ __forceinline__ short f2b(float x) {
    __hip_bfloat16 h = __float2bfloat16(x);
    return *(short*)&h;
}

__device__ __forceinline__ void gl_lds16(void* lds_uniform, const void* gptr) {
    __builtin_amdgcn_global_load_lds(
        (const __attribute__((address_space(1))) void*)gptr,
        (__attribute__((address_space(3))) void*)lds_uniform,
        16, 0, 0);
}

// ---------------------------------------------------------------------------
// K1 (MFMA): parts[split][bh][v][k] = sum_{s in split} V[bh][s][v]*phi(K[bh][s][k])
//            nrm[bh][k]            += sum_s phi(K[bh][s][k])   (atomic, 64KB)
// grid (8 s-splits, 128 bh), 256 threads (4 waves, each a 64v x 64k quadrant).
// 8 splits (was 4): 1024 blocks -> 3-4 blocks/CU so global-load latency and
// the per-chunk sync serialization are covered by TLP (was grid-limited 2/CU).
// ---------------------------------------------------------------------------
__global__ __launch_bounds__(256) void k1_memory(
    const float* __restrict__ Kin, const float* __restrict__ Vin,
    float* __restrict__ parts, float* __restrict__ nrm)
{
    const int split = blockIdx.x;   // 0..7, 256 s-rows each
    const int bh = blockIdx.y;
    const int t = threadIdx.x;
    const int wave = t >> 6, lane = t & 63;
    const int lm = lane & 15, quad = lane >> 4;
    const int wm = wave >> 1, wn = wave & 1;    // v-half, k-half

    __shared__ __hip_bfloat16 sVt[128*72];      // [v][s]  18KB
    __shared__ __hip_bfloat16 sKt[128*72];      // [k][s]  18KB

    const long base = (long)bh * S_ * D_ + (long)split * (S_/8) * D_;
    const float* Kp = Kin + base;
    const float* Vp = Vin + base;

    f32x4 acc[4][4];
#pragma unroll
    for (int i = 0; i < 4; ++i)
#pragma unroll
        for (int j = 0; j < 4; ++j) { f32x4 z = {0.f,0.f,0.f,0.f}; acc[i][j] = z; }

    float na[2][4] = {{0.f,0.f,0.f,0.f},{0.f,0.f,0.f,0.f}};

    const int si  = t & 15;          // s-quad within chunk (0..15)
    const int dj0 = t >> 4;          // 0..15 (d-quad base)

    for (int c = 0; c < 4; ++c) {    // 4 chunks of 64 s-rows
        const int s0 = c*64 + si*4;
        __syncthreads();             // previous chunk's readers done
#pragma unroll
        for (int m = 0; m < 2; ++m) {
            const int dj = dj0 + 16*m;              // d-quad 0..31
            const float* gK = Kp + (long)s0*D_ + dj*4;
            const float* gV = Vp + (long)s0*D_ + dj*4;
            float4 krv[4], vrv[4];
#pragma unroll
            for (int r = 0; r < 4; ++r) {
                krv[r] = *(const float4*)(gK + (long)r*D_);
                vrv[r] = *(const float4*)(gV + (long)r*D_);
            }
            const float* kf = (const float*)krv;    // kf[r*4+cc]
            const float* vf = (const float*)vrv;
#pragma unroll
            for (int cc = 0; cc < 4; ++cc) {
                float p0 = phi_f(kf[0*4+cc]), p1 = phi_f(kf[1*4+cc]);
                float p2 = phi_f(kf[2*4+cc]), p3 = phi_f(kf[3*4+cc]);
                na[m][cc] += p0 + p1 + p2 + p3;
                s16x4 pw; pw[0]=f2b(p0); pw[1]=f2b(p1); pw[2]=f2b(p2); pw[3]=f2b(p3);
                s16x4 vw; vw[0]=f2b(vf[0*4+cc]); vw[1]=f2b(vf[1*4+cc]);
                          vw[2]=f2b(vf[2*4+cc]); vw[3]=f2b(vf[3*4+cc]);
                const int d = dj*4 + cc;
                *(s16x4*)(sKt + d*72 + si*4) = pw;
                *(s16x4*)(sVt + d*72 + si*4) = vw;
            }
        }
        __syncthreads();
#pragma unroll
        for (int kh = 0; kh < 2; ++kh) {
            const int scol = kh*32 + quad*8;
            bf16x8 af[4], bfr[4];
#pragma unroll
            for (int x = 0; x < 4; ++x) {
                af[x]  = *(const bf16x8*)(sVt + (wm*64 + x*16 + lm)*72 + scol);
                bfr[x] = *(const bf16x8*)(sKt + (wn*64 + x*16 + lm)*72 + scol);
            }
#pragma unroll
            for (int mt = 0; mt < 4; ++mt)
#pragma unroll
                for (int nt = 0; nt < 4; ++nt)
                    acc[mt][nt] = __builtin_amdgcn_mfma_f32_16x16x32_bf16(
                        af[mt], bfr[nt], acc[mt][nt], 0, 0, 0);
        }
    }

    // norm: reduce na over the 16 threads sharing dj (lane bits 0-3 = si)
#pragma unroll
    for (int m = 0; m < 2; ++m)
#pragma unroll
        for (int cc = 0; cc < 4; ++cc) {
            float v = na[m][cc];
            v += __shfl_xor(v, 1); v += __shfl_xor(v, 2);
            v += __shfl_xor(v, 4); v += __shfl_xor(v, 8);
            if (si == 0)
                atomicAdd(&nrm[bh*D_ + (dj0 + 16*m)*4 + cc], v);
        }

    // epilogue: plain stores to this split's partial. C/D: col=k, row=v (quad*4+reg)
    float* mp = parts + ((long)split*BH_ + bh) * (D_*D_);
#pragma unroll
    for (int mt = 0; mt < 4; ++mt)
#pragma unroll
        for (int nt = 0; nt < 4; ++nt) {
            const int kcol = wn*64 + nt*16 + lm;
#pragma unroll
            for (int r = 0; r < 4; ++r) {
                const int vrow = wm*64 + mt*16 + quad*4 + r;
                mp[vrow*D_ + kcol] = acc[mt][nt][r];
            }
        }
}

// ---------------------------------------------------------------------------
// K1b: memTb[bh][row][seg] (bf16, 16B segs, PRE-SWIZZLED seg^(row&15)) =
//      sum over 8 split partials. Lets k2 stage via linear global_load_lds
// while its ds_reads apply the same seg-XOR (rule #21).
// 262144 segs -> 1024 blocks x 256.
// ---------------------------------------------------------------------------
__global__ __launch_bounds__(256) void k1b_finalize(
    const float* __restrict__ parts, __hip_bfloat16* __restrict__ memTb)
{
    const long g = (long)blockIdx.x*256 + threadIdx.x;  // 0..262143
    const int bh  = (int)(g >> 11);
    const int rem = (int)(g & 2047);
    const int row = rem >> 4, seg = rem & 15;
    const int srcSeg = seg ^ (row & 15);
    const long sbase = (long)bh*(D_*D_) + row*D_ + srcSeg*8;

    f32x4 s0 = {0.f,0.f,0.f,0.f}, s1 = {0.f,0.f,0.f,0.f};
#pragma unroll
    for (int sp = 0; sp < 8; ++sp) {
        const float* p = parts + (long)sp*BH_*(D_*D_) + sbase;
        s0 += *(const f32x4*)p;
        s1 += *(const f32x4*)(p + 4);
    }
    bf16x8 ob;
#pragma unroll
    for (int j = 0; j < 4; ++j) { ob[j] = f2b(s0[j]); ob[4+j] = f2b(s1[j]); }
    *(bf16x8*)(memTb + g*8) = ob;
}

// ---------------------------------------------------------------------------
// K2 (MFMA): retrieved = phi(Q) @ mem ; denom = phi(Q)·norm ;
//            attn = gw*retrieved/denom + lw*local ; bf16 out to [B,S,H*D]
// grid (16 s-blocks of 128 rows, 128 bh), 256 threads (4 waves, 64s x 64v).
// Denom: 2-level reduce (2 shfl + 8 LDS partials/row + one pass) instead of
// the 5-deep shfl chain -> removes 48 serial DS-pipe ops/thread from staging.
// ---------------------------------------------------------------------------
__global__ __launch_bounds__(256) void k2_retrieve(
    const float* __restrict__ Qin, const float* __restrict__ Lin,
    const float* __restrict__ bal,
    const __hip_bfloat16* __restrict__ memTb, const float* __restrict__ nrm,
    __hip_bfloat16* __restrict__ attnB)
{
    const int sc = blockIdx.x;    // 0..15
    const int bh = blockIdx.y;
    const int b = bh >> 5, h = bh & 31;
    const int t = threadIdx.x;
    const int wave = t >> 6, lane = t & 63;
    const int lm = lane & 15, quad = lane >> 4;
    const int wm = wave >> 1, wn = wave & 1;    // s-half, v-half

    __shared__ char smem[128*132*4];            // 67,584 B (staging + epilogue)
    __hip_bfloat16* sQ = (__hip_bfloat16*)smem;             // 32 KB [s][k] swz
    __hip_bfloat16* sM = (__hip_bfloat16*)(smem + 32768);   // 32 KB [v][k] swz
    float* sOut = (float*)smem;                              // epilogue reuse
    __shared__ float sDenP[128][8];             // 4 KB partials
    __shared__ float sDen[128];

    const float* Qp = Qin + (long)bh*S_*D_ + (long)sc*128*D_;
    const float* Lp = Lin + (long)bh*S_*D_ + (long)sc*128*D_;
    const __hip_bfloat16* mb = memTb + (long)bh*(D_*D_);

    // 1) issue sM staging first (latency hides under Q's phi work)
#pragma unroll
    for (int i = 0; i < 8; ++i)
        gl_lds16((void*)(sM + (i*256 + wave*64)*8),
                 (const void*)(mb + (long)(i*256 + wave*64 + lane)*8));

    // 2) Q: phi + denom partial + bf16 swizzled write
    const int kq = t & 31;                       // k-quad (constant across i)
    const float4 nq = *(const float4*)(nrm + bh*D_ + kq*4);
#pragma unroll
    for (int i = 0; i < 16; ++i) {
        const int idx = t + i*256;               // float4 index over 128x32
        const int row = idx >> 5;                // = (t>>5) + 8i
        float4 qv = *(const float4*)(Qp + (long)idx*4);
        float p0 = phi_f(qv.x), p1 = phi_f(qv.y), p2 = phi_f(qv.z), p3 = phi_f(qv.w);
        float part = p0*nq.x + p1*nq.y + p2*nq.z + p3*nq.w;
        part += __shfl_xor(part, 1);
        part += __shfl_xor(part, 2);
        if ((kq & 3) == 0) sDenP[row][kq >> 2] = part;
        const int seg = kq >> 1, half = kq & 1;
        const int off = row*128 + ((seg ^ (row & 15)) << 3) + half*4;
        s16x4 qw; qw[0]=f2b(p0); qw[1]=f2b(p1); qw[2]=f2b(p2); qw[3]=f2b(p3);
        *(s16x4*)(sQ + off) = qw;
    }
    __syncthreads();   // drains vmcnt(0): sM staged; sQ/sDenP visible

    // finish denom (one cheap pass; consumed after the next barrier)
    if (t < 128) {
        float d = 0.f;
#pragma unroll
        for (int j = 0; j < 8; ++j) d += sDenP[t][j];
        sDen[t] = d;
    }

    f32x4 acc[4][4];
#pragma unroll
    for (int i = 0; i < 4; ++i)
#pragma unroll
        for (int j = 0; j < 4; ++j) { f32x4 z = {0.f,0.f,0.f,0.f}; acc[i][j] = z; }

#pragma unroll
    for (int kh = 0; kh < 4; ++kh) {
        const int segk = kh*4 + quad;            // 16B k-seg 0..15
        bf16x8 af[4], bfr[4];
#pragma unroll
        for (int x = 0; x < 4; ++x) {
            const int srow = wm*64 + x*16 + lm;
            af[x]  = *(const bf16x8*)(sQ + srow*128 + ((segk ^ (srow & 15)) << 3));
            const int vrow = wn*64 + x*16 + lm;
            bfr[x] = *(const bf16x8*)(sM + vrow*128 + ((segk ^ (vrow & 15)) << 3));
        }
#pragma unroll
        for (int mt = 0; mt < 4; ++mt)
#pragma unroll
            for (int nt = 0; nt < 4; ++nt)
                acc[mt][nt] = __builtin_amdgcn_mfma_f32_16x16x32_bf16(
                    af[mt], bfr[nt], acc[mt][nt], 0, 0, 0);
    }

    const float bv = bal[h];
    const float gw = 1.f/(1.f+__expf(-bv));
    const float lw = 1.f/(1.f+__expf(-(1.f-bv)));

    // ---- epilogue pass A: scaled acc -> LDS fp32 [128][132] (2-way = free)
    __syncthreads();   // all waves done reading sQ/sM; sDen visible
#pragma unroll
    for (int mt = 0; mt < 4; ++mt)
#pragma unroll
        for (int r = 0; r < 4; ++r) {
            const int srow = wm*64 + mt*16 + quad*4 + r;
            const float scale = gw / sDen[srow];
#pragma unroll
            for (int nt = 0; nt < 4; ++nt)
                sOut[srow*132 + wn*64 + nt*16 + lm] = acc[mt][nt][r]*scale;
        }
    __syncthreads();

    // ---- epilogue pass B: fused + vectorized (16B loads/stores)
    const int seg = t & 15;                      // 16B out-seg (8 bf16)
#pragma unroll
    for (int i = 0; i < 8; ++i) {
        const int row = (t >> 4) + i*16;         // 0..127
        const float* Lr = Lp + (long)row*D_ + seg*8;
        const float* Or = sOut + row*132 + seg*8;
        float4 l0 = *(const float4*)Lr;
        float4 l1 = *(const float4*)(Lr + 4);
        f32x4 o0 = *(const f32x4*)Or;
        f32x4 o1 = *(const f32x4*)(Or + 4);
        bf16x8 ob;
        ob[0] = f2b(o0[0] + lw*l0.x); ob[1] = f2b(o0[1] + lw*l0.y);
        ob[2] = f2b(o0[2] + lw*l0.z); ob[3] = f2b(o0[3] + lw*l0.w);
        ob[4] = f2b(o1[0] + lw*l1.x); ob[5] = f2b(o1[1] + lw*l1.y);
        ob[6] = f2b(o1[2] + lw*l1.z); ob[7] = f2b(o1[3] + lw*l1.w);
        const long oidx = ((long)b*S_ + sc*128 + row)*DM_ + h*D_ + seg*8;
        *(bf16x8*)(attnB + oidx) = ob;
    }
}

// ---------------------------------------------------------------------------
// w_o fp32 -> bf16
// ---------------------------------------------------------------------------
__global__ __launch_bounds__(256) void kconv(
    const float* __restrict__ w, __hip_bfloat16* __restrict__ wb)
{
    long i = ((long)blockIdx.x*256 + threadIdx.x)*4;
    float4 f = *(const float4*)(w + i);
    __hip_bfloat16 ob[4] = {__float2bfloat16(f.x), __float2bfloat16(f.y),
                            __float2bfloat16(f.z), __float2bfloat16(f.w)};
    *(uint2*)(wb + i) = *(uint2*)ob;
}

// ---------------------------------------------------------------------------
// K3: Y[8192,4096] = X[8192,4096] @ W[4096,4096]^T   (bf16 MFMA, fp32 out)
// 256x256 8-phase template: BK=64, 8 waves (2Mx4N), 512 threads, 128KiB LDS
// dbuf, counted vmcnt(8), raw s_barrier, setprio, seg-XOR swizzle.
// R4 delta: stage burst split by buffer-half lifetime — B(t+2) issued at
// phase 2 (B-buf free after ph1's closing barrier), A(t+2) at phase 3
// (A free after ph2). Earlier issue, smaller bursts, same vmcnt accounting.
// ---------------------------------------------------------------------------
#define GBM 256
#define GBN 256
#define GBK 64
#define GNT (DM_/GBK)   // 64 K-tiles

__device__ __forceinline__ bf16x8 ldfrag(const __hip_bfloat16* base, int row, int k) {
    const int kk = k ^ ((row & 7) << 3);
    return *(const bf16x8*)(base + row * GBK + kk);
}

__device__ __forceinline__ void stage_half(
    const __hip_bfloat16* __restrict__ G, __hip_bfloat16* sb,
    int r0g, int kb, int wave, int lane)
{
#pragma unroll
    for (int r = 0; r < 4; ++r) {
        const int c   = r * 512 + wave * 64 + lane;        // 16B chunk id 0..2047
        const int row = c >> 3;
        const int ko  = ((c & 7) ^ (row & 7)) * 8;         // pre-swizzled source seg
        gl_lds16((void*)(sb + (r * 512 + wave * 64) * 8),
                 (const void*)(G + (long)(r0g + row) * DM_ + kb + ko));
    }
}

__global__ __launch_bounds__(512, 2) void k3_gemm(
    const __hip_bfloat16* __restrict__ X,
    const __hip_bfloat16* __restrict__ W,
    float* __restrict__ Y)
{
    __shared__ alignas(16) __hip_bfloat16 sA[2][GBM * GBK];   // 64 KiB
    __shared__ alignas(16) __hip_bfloat16 sB[2][GBN * GBK];   // 64 KiB

    const int tid = threadIdx.x;
    const int wave = tid >> 6, lane = tid & 63;
    const int lm = lane & 15, quad = lane >> 4;
    const int wm = wave >> 2, wn = wave & 3;     // 2M x 4N waves

    const int orig = blockIdx.x;
    const int wg = (orig & 7) * 64 + (orig >> 3);
    const int m0 = (wg >> 4) * GBM;
    const int n0 = (wg & 15) * GBN;

    f32x4 acc[8][4];
#pragma unroll
    for (int i = 0; i < 8; ++i)
#pragma unroll
        for (int j = 0; j < 4; ++j) { f32x4 z = {0.f,0.f,0.f,0.f}; acc[i][j] = z; }

    const int ar0 = wm * 128 + lm;
    const int br0 = wn * 64 + lm;
    const int kq  = quad * 8;

    // prologue: per tile issue B then A (matches steady-state order)
    stage_half(W, sB[0], n0, 0, wave, lane);
    stage_half(X, sA[0], m0, 0, wave, lane);
    stage_half(W, sB[1], n0, GBK, wave, lane);
    stage_half(X, sA[1], m0, GBK, wave, lane);
    asm volatile("s_waitcnt vmcnt(8)" ::: "memory");
    __builtin_amdgcn_s_barrier();

    bf16x8 a[4][2], b[4][2];

    for (int t = 0; t < GNT; ++t) {
        const int cur = t & 1;
        const __hip_bfloat16* As = sA[cur];
        const __hip_bfloat16* Bs = sB[cur];

        // phase 0: ds_read a-low (8) + b01 (4); MFMA Q(low, n01)
#pragma unroll
        for (int mf = 0; mf < 4; ++mf)
#pragma unroll
            for (int kh = 0; kh < 2; ++kh)
                a[mf][kh] = ldfrag(As, ar0 + mf * 16, kh * 32 + kq);
#pragma unroll
        for (int nf = 0; nf < 2; ++nf)
#pragma unroll
            for (int kh = 0; kh < 2; ++kh)
                b[nf][kh] = ldfrag(Bs, br0 + nf * 16, kh * 32 + kq);
        __builtin_amdgcn_s_barrier();
        asm volatile("s_waitcnt lgkmcnt(0)" ::: "memory");
        __builtin_amdgcn_sched_barrier(0);
        __builtin_amdgcn_s_setprio(1);
#pragma unroll
        for (int mf = 0; mf < 4; ++mf)
#pragma unroll
            for (int nf = 0; nf < 2; ++nf)
#pragma unroll
                for (int kh = 0; kh < 2; ++kh)
                    acc[mf][nf] = __builtin_amdgcn_mfma_f32_16x16x32_bf16(
                        a[mf][kh], b[nf][kh], acc[mf][nf], 0, 0, 0);
        __builtin_amdgcn_s_setprio(0);
        __builtin_amdgcn_s_barrier();

        // phase 1: ds_read b23 (4); MFMA Q(low, n23). B-buf fully read after
        // this phase's closing barrier.
#pragma unroll
        for (int nf = 2; nf < 4; ++nf)
#pragma unroll
            for (int kh = 0; kh < 2; ++kh)
                b[nf][kh] = ldfrag(Bs, br0 + nf * 16, kh * 32 + kq);
        __builtin_amdgcn_s_barrier();
        asm volatile("s_waitcnt lgkmcnt(0)" ::: "memory");
        __builtin_amdgcn_sched_barrier(0);
        __builtin_amdgcn_s_setprio(1);
#pragma unroll
        for (int mf = 0; mf < 4; ++mf)
#pragma unroll
            for (int nf = 2; nf < 4; ++nf)
#pragma unroll
                for (int kh = 0; kh < 2; ++kh)
                    acc[mf][nf] = __builtin_amdgcn_mfma_f32_16x16x32_bf16(
                        a[mf][kh], b[nf][kh], acc[mf][nf], 0, 0, 0);
        __builtin_amdgcn_s_setprio(0);
        __builtin_amdgcn_s_barrier();

        // phase 2: stage B(t+2) into cur (safe: B reads done); ds_read a-high;
        // MFMA Q(high, n01). A-buf fully read after this phase's closing barrier.
        if (t + 2 < GNT)
            stage_half(W, sB[cur], n0, (t + 2) * GBK, wave, lane);
#pragma unroll
        for (int mf = 0; mf < 4; ++mf)
#pragma unroll
            for (int kh = 0; kh < 2; ++kh)
                a[mf][kh] = ldfrag(As, ar0 + 64 + mf * 16, kh * 32 + kq);
        __builtin_amdgcn_s_barrier();
        asm volatile("s_waitcnt lgkmcnt(0)" ::: "memory");
        __builtin_amdgcn_sched_barrier(0);
        __builtin_amdgcn_s_setprio(1);
#pragma unroll
        for (int mf = 0; mf < 4; ++mf)
#pragma unroll
            for (int nf = 0; nf < 2; ++nf)
#pragma unroll
                for (int kh = 0; kh < 2; ++kh)
                    acc[4 + mf][nf] = __builtin_amdgcn_mfma_f32_16x16x32_bf16(
                        a[mf][kh], b[nf][kh], acc[4 + mf][nf], 0, 0, 0);
        __builtin_amdgcn_s_setprio(0);
        __builtin_amdgcn_s_barrier();

        // phase 3: stage A(t+2) into cur (safe: A reads done); MFMA Q(high,n23);
        // counted vmcnt(8) -> t+1 landed, t+2's 8 loads stay in flight.
        if (t + 2 < GNT)
            stage_half(X, sA[cur], m0, (t + 2) * GBK, wave, lane);
        __builtin_amdgcn_s_barrier();
        __builtin_amdgcn_s_setprio(1);
#pragma unroll
        for (int mf = 0; mf < 4; ++mf)
#pragma unroll
            for (int nf = 2; nf < 4; ++nf)
#pragma unroll
                for (int kh = 0; kh < 2; ++kh)
                    acc[4 + mf][nf] = __builtin_amdgcn_mfma_f32_16x16x32_bf16(
                        a[mf][kh], b[nf][kh], acc[4 + mf][nf], 0, 0, 0);
        __builtin_amdgcn_s_setprio(0);
        if (t + 2 < GNT)
            asm volatile("s_waitcnt vmcnt(8)" ::: "memory");
        else
            asm volatile("s_waitcnt vmcnt(0)" ::: "memory");
        __builtin_amdgcn_s_barrier();
    }

#pragma unroll
    for (int mf = 0; mf < 8; ++mf) {
        const int row = m0 + wm * 128 + mf * 16 + quad * 4;
#pragma unroll
        for (int nf = 0; nf < 4; ++nf) {
            const int col = n0 + wn * 64 + nf * 16 + lm;
#pragma unroll
            for (int r = 0; r < 4; ++r)
                Y[(long)(row + r) * DM_ + col] = acc[mf][nf][r];
        }
    }
}

// ---------------------------------------------------------------------------
extern "C" void kernel_launch(void* const* d_in, const int* in_sizes, int n_in,
                              void* d_out, int out_size, void* d_ws, size_t ws_size,
                              hipStream_t stream) {
    const float* Q   = (const float*)d_in[0];
    const float* K   = (const float*)d_in[1];
    const float* V   = (const float*)d_in[2];
    const float* L   = (const float*)d_in[3];
    const float* bal = (const float*)d_in[4];
    const float* Wo  = (const float*)d_in[5];
    float* Y = (float*)d_out;

    char* ws = (char*)d_ws;
    // Lifetime-disjoint overlap (stream order k1 -> k1b -> kconv -> k2 -> k3):
    //   [0, 64MB):  parts (k1 out, k1b in; dead before k2)
    //   [0, 64MB):  attnB (k2 out, k3 in) — same region, later lifetime
    float* parts = (float*)ws;                                   // 67,108,864 B
    __hip_bfloat16* attnB = (__hip_bfloat16*)ws;                 // same region
    __hip_bfloat16* woB = (__hip_bfloat16*)(ws + 67108864);      // 33,554,432 B
    float* nrm   = (float*)(ws + 100663296);                     //    65,536 B
    __hip_bfloat16* memTb = (__hip_bfloat16*)(ws + 100728832);   //  4,194,304 B
    // total 104,923,136 B (same footprint as last round)

    // only the 64KB norm accumulator needs zeroing
    hipMemsetAsync(nrm, 0, 65536, stream);

    k1_memory<<<dim3(8, BH_), 256, 0, stream>>>(K, V, parts, nrm);
    k1b_finalize<<<1024, 256, 0, stream>>>(parts, memTb);
    kconv<<<DM_*DM_/4/256, 256, 0, stream>>>(Wo, woB);
    k2_retrieve<<<dim3(S_/128, BH_), 256, 0, stream>>>(Q, L, bal, memTb, nrm, attnB);
    k3_gemm<<<dim3(512), 512, 0, stream>>>(attnB, woB, Y);
}